// Round 4
// baseline (307.545 us; speedup 1.0000x reference)
//
#include <hip/hip_runtime.h>
#include <cstddef>
#include <cstdint>

typedef unsigned short u16;
typedef __attribute__((ext_vector_type(8))) unsigned short ushort8;
typedef __attribute__((ext_vector_type(8))) short bf16x8;   // 8 bf16 bit-patterns (4 VGPRs)
typedef __attribute__((ext_vector_type(4))) float f32x4;

#define DEV __device__ __forceinline__

DEV u16 f2bf(float f){
  uint32_t u = __builtin_bit_cast(uint32_t, f);
  u += 0x7FFFu + ((u >> 16) & 1u);          // RNE
  return (u16)(u >> 16);
}
DEV float silu_f(float x){ return x / (1.f + __expf(-x)); }

// ---------------- fused transposes: fp32 [R][C] -> bf16 [Cout][R] ----------------
__global__ __launch_bounds__(256) void prep_k(const float* __restrict__ x,
    const float* __restrict__ gcn_w, const float* __restrict__ w_in,
    const float* __restrict__ w_out, const float* __restrict__ w_xp,
    u16* __restrict__ xT, u16* __restrict__ gcnT, u16* __restrict__ w_inT,
    u16* __restrict__ w_outT, u16* __restrict__ w_xpT){
  __shared__ u16 tile[32][33];
  int b = blockIdx.x;
  const float* in; u16* out; int R, C, Cout, bx, by;
  if (b < 1024)      { in=x;     out=xT;     R=4096; C=256;  Cout=256;  bx=b&7;  by=b>>3; }
  else if (b < 1088) { b-=1024; in=gcn_w; out=gcnT;   R=256; C=256;  Cout=256;  bx=b&7;  by=b>>3; }
  else if (b < 1344) { b-=1088; in=w_in;  out=w_inT;  R=256; C=1024; Cout=1024; bx=b&31; by=b>>5; }
  else if (b < 1472) { b-=1344; in=w_out; out=w_outT; R=512; C=256;  Cout=256;  bx=b&7;  by=b>>3; }
  else               { b-=1472; in=w_xp;  out=w_xpT;  R=512; C=48;   Cout=64;   bx=b&1;  by=b>>1; }
  int c0 = bx*32, r0 = by*32, tx = threadIdx.x, ty = threadIdx.y;   // block (32,8)
  #pragma unroll
  for (int k = 0; k < 4; ++k){
    int r = r0 + ty + k*8, c = c0 + tx;
    float v = (c < C) ? in[(size_t)r * C + c] : 0.f;
    tile[ty + k*8][tx] = f2bf(v);
  }
  __syncthreads();
  #pragma unroll
  for (int k = 0; k < 4; ++k){
    int oc = c0 + ty + k*8, orr = r0 + tx;
    if (oc < Cout) out[(size_t)oc * R + orr] = tile[tx][ty + k*8];
  }
}

// ---------------- generic bf16-MFMA GEMM with register-prefetch pipeline ------
// C[M,N] = A_fp32[M,K] @ B, B pre-transposed bf16 [N][K] (ldb=K).
// NPART>1: A is the sum of NPART partial buffers spaced pastr floats apart.
// MODE: 0 = plain store to out0 + blockIdx.z*postr (256-wide output)
//       1 = +bias, ReLU, LayerNorm(256) -> out0 fp32
//       2 = split store: cols<512 -> out0, else -> out1 (both 512-wide)
template<int MODE, int TM, int NT, int NTHR, int NPART>
__global__ __launch_bounds__(NTHR) void gemm_k(const float* __restrict__ A, int lda, long long pastr,
    const u16* __restrict__ Bt, int ldb, int kchunk,
    float* __restrict__ out0, long long postr, float* __restrict__ out1,
    const float* __restrict__ bias, const float* __restrict__ lng, const float* __restrict__ lnb)
{
  constexpr int NW = NTHR/64, WR = NW/4, WM = TM/WR, WN = NT/4;
  constexpr int MI = WM/16, NI = WN/16;
  extern __shared__ char smem[];
  u16* As = (u16*)smem;                 // TM x 40
  u16* Bs = As + TM * 40;               // NT x 40
  const int tid = threadIdx.x, wave = tid >> 6, lane = tid & 63;
  const int lq = lane >> 4, lr = lane & 15;
  const int wm = wave >> 2, wn = wave & 3;
  const int m0 = blockIdx.x * TM, n0g = blockIdx.y * NT;
  const int k0base = blockIdx.z * kchunk;

  f32x4 acc[MI][NI];
  #pragma unroll
  for (int i = 0; i < MI; ++i)
    #pragma unroll
    for (int j = 0; j < NI; ++j) acc[i][j] = f32x4{0.f, 0.f, 0.f, 0.f};

  const int arow = tid >> 2, ako = (tid & 3) * 8;
  const bool aact = (tid < TM * 4);
  const bool bact = (tid < NT);
  const float* aptr = A + (size_t)(m0 + arow) * lda + k0base + ako;
  const u16*   bptr = Bt + (size_t)(n0g + tid) * ldb + k0base;

  f32x4 fa0[NPART], fa1[NPART];
  ushort8 bv[4];
  if (aact){
    #pragma unroll
    for (int p = 0; p < NPART; ++p){
      fa0[p] = *(const f32x4*)(aptr + (size_t)p * pastr);
      fa1[p] = *(const f32x4*)(aptr + (size_t)p * pastr + 4);
    }
  }
  if (bact){
    const ushort8* bp = (const ushort8*)bptr;
    #pragma unroll
    for (int j = 0; j < 4; ++j) bv[j] = bp[j];
  }

  for (int kk = 0; kk < kchunk; kk += 32){
    if (aact){
      f32x4 s0 = fa0[0], s1 = fa1[0];
      #pragma unroll
      for (int p = 1; p < NPART; ++p){ s0 += fa0[p]; s1 += fa1[p]; }
      ushort8 o;
      #pragma unroll
      for (int j = 0; j < 4; ++j) o[j] = f2bf(s0[j]);
      #pragma unroll
      for (int j = 0; j < 4; ++j) o[4 + j] = f2bf(s1[j]);
      *(ushort8*)(As + arow * 40 + ako) = o;
    }
    if (bact){
      ushort8* dst = (ushort8*)(Bs + tid * 40);
      #pragma unroll
      for (int j = 0; j < 4; ++j) dst[j] = bv[j];
    }
    __syncthreads();
    if (kk + 32 < kchunk){
      aptr += 32; bptr += 32;
      if (aact){
        #pragma unroll
        for (int p = 0; p < NPART; ++p){
          fa0[p] = *(const f32x4*)(aptr + (size_t)p * pastr);
          fa1[p] = *(const f32x4*)(aptr + (size_t)p * pastr + 4);
        }
      }
      if (bact){
        const ushort8* bp = (const ushort8*)bptr;
        #pragma unroll
        for (int j = 0; j < 4; ++j) bv[j] = bp[j];
      }
    }
    bf16x8 af[MI], bfr[NI];
    #pragma unroll
    for (int mi = 0; mi < MI; ++mi)
      af[mi] = *(const bf16x8*)(As + (wm * WM + mi * 16 + lr) * 40 + lq * 8);
    #pragma unroll
    for (int ni = 0; ni < NI; ++ni)
      bfr[ni] = *(const bf16x8*)(Bs + (wn * WN + ni * 16 + lr) * 40 + lq * 8);
    #pragma unroll
    for (int mi = 0; mi < MI; ++mi)
      #pragma unroll
      for (int ni = 0; ni < NI; ++ni)
        acc[mi][ni] = __builtin_amdgcn_mfma_f32_16x16x32_bf16(af[mi], bfr[ni], acc[mi][ni], 0, 0, 0);
    __syncthreads();
  }

  if constexpr (MODE == 1){
    float* Hs  = (float*)(smem + TM * 80 + NT * 80);   // TM x 257
    float* mus = Hs + TM * 257;
    float* rss = mus + TM;
    #pragma unroll
    for (int mi = 0; mi < MI; ++mi)
      #pragma unroll
      for (int ni = 0; ni < NI; ++ni)
        #pragma unroll
        for (int r = 0; r < 4; ++r){
          int row_l = wm*WM + mi*16 + lq*4 + r;
          int col_l = wn*WN + ni*16 + lr;
          Hs[row_l*257 + col_l] = fmaxf(acc[mi][ni][r] + bias[col_l], 0.f);
        }
    __syncthreads();
    for (int r = wave; r < TM; r += NW){
      float s = 0.f, s2 = 0.f;
      #pragma unroll
      for (int j = 0; j < 4; ++j){
        float v = Hs[r*257 + lane + j*64];
        s += v; s2 += v*v;
      }
      #pragma unroll
      for (int d = 32; d; d >>= 1){
        s  += __shfl_down(s, d);
        s2 += __shfl_down(s2, d);
      }
      if (lane == 0){
        float mu  = s * (1.f/256.f);
        float var = s2 * (1.f/256.f) - mu*mu;
        mus[r] = mu; rss[r] = rsqrtf(var + 1e-5f);
      }
    }
    __syncthreads();
    for (int idx = tid; idx < TM*256; idx += NTHR){
      int r = idx >> 8, c = idx & 255;
      float v = (Hs[r*257 + c] - mus[r]) * rss[r] * lng[c] + lnb[c];
      out0[(size_t)(m0 + r) * 256 + c] = v;
    }
  } else {
    #pragma unroll
    for (int mi = 0; mi < MI; ++mi)
      #pragma unroll
      for (int ni = 0; ni < NI; ++ni)
        #pragma unroll
        for (int r = 0; r < 4; ++r){
          float v = acc[mi][ni][r];
          int row  = m0 + wm*WM + mi*16 + lq*4 + r;
          int gcol = n0g + wn*WN + ni*16 + lr;
          if constexpr (MODE == 0){
            out0[(size_t)blockIdx.z * postr + (size_t)row * 256 + gcol] = v;
          } else {
            if (gcol < 512) out0[(size_t)row * 512 + gcol] = v;
            else            out1[(size_t)row * 512 + gcol - 512] = v;
          }
        }
  }
}

// ---------------- fused: conv+silu -> dbc (MFMA) -> dt -> scan phase 1 ----------
// chunk = 16 timesteps; grid 256 blocks x 512 threads; thread = channel d.
// __launch_bounds__(512,2): allow 256 VGPRs so ureg/h/Aa/wdt stay in registers.
__global__ __launch_bounds__(512, 2) void mid_k(const float* __restrict__ xc,
    const float* __restrict__ cw, const float* __restrict__ cb,
    const u16* __restrict__ w_xpT, const float* __restrict__ w_dt,
    const float* __restrict__ b_dt, const float* __restrict__ A_log,
    float* __restrict__ u_g, float* __restrict__ dbc_g,
    float* __restrict__ dAc, float* __restrict__ hend)
{
  __shared__ u16 uL[16 * 520];            // 16,640 B
  __shared__ float dbc2[2][16][64];       // 8,192 B (reduced in-place into [0])
  const int tid = threadIdx.x, d = tid;
  const int c = blockIdx.x, t0 = c * 16;
  const float w0 = cw[d*4+0], w1 = cw[d*4+1], w2 = cw[d*4+2], w3 = cw[d*4+3];
  const float cbd = cb[d];
  float xm3 = 0.f, xm2 = 0.f, xm1 = 0.f;
  if (c > 0){
    xm3 = xc[(size_t)(t0-3)*512 + d];
    xm2 = xc[(size_t)(t0-2)*512 + d];
    xm1 = xc[(size_t)(t0-1)*512 + d];
  }
  float ureg[16];
  #pragma unroll
  for (int t = 0; t < 16; ++t){
    float x0 = xc[(size_t)(t0+t)*512 + d];
    float a = cbd + xm3*w0 + xm2*w1 + xm1*w2 + x0*w3;
    float uu = silu_f(a);
    ureg[t] = uu;
    uL[t*520 + d] = f2bf(uu);
    u_g[(size_t)(t0+t)*512 + d] = uu;
    xm3 = xm2; xm2 = xm1; xm1 = x0;
  }
  __syncthreads();
  // dbc[16x48(+pad)] = u[16x512] @ w_xp[512x64]; 8 waves = 4 n-tiles x 2 K-halves
  const int wave = tid >> 6, lane = tid & 63, lq = lane >> 4, lr = lane & 15;
  const int nt = wave & 3, kh = wave >> 2;
  f32x4 dacc{0.f, 0.f, 0.f, 0.f};
  #pragma unroll
  for (int kk = kh*256; kk < kh*256 + 256; kk += 32){
    bf16x8 aF = *(const bf16x8*)(uL + lr*520 + kk + lq*8);
    bf16x8 bF = *(const bf16x8*)(w_xpT + (size_t)(nt*16 + lr)*512 + kk + lq*8);
    dacc = __builtin_amdgcn_mfma_f32_16x16x32_bf16(aF, bF, dacc, 0, 0, 0);
  }
  #pragma unroll
  for (int r = 0; r < 4; ++r) dbc2[kh][lq*4 + r][nt*16 + lr] = dacc[r];
  __syncthreads();
  for (int i = tid; i < 16*64; i += 512){
    int r = i >> 6, j = i & 63;
    float v = dbc2[0][r][j] + dbc2[1][r][j];
    dbc2[0][r][j] = v;
    if (j < 48) dbc_g[(size_t)(t0 + r)*48 + j] = v;
  }
  __syncthreads();
  // dt = softplus(dbc[:, :16] @ w_dt + b_dt); local scan from zero state
  float wdt[16];
  #pragma unroll
  for (int r = 0; r < 16; ++r) wdt[r] = w_dt[r*512 + d];
  const float bdt = b_dt[d];
  float Aa[16], h[16];
  #pragma unroll
  for (int s = 0; s < 16; ++s){ Aa[s] = -__expf(A_log[d*16 + s]); h[s] = 0.f; }
  float ds = 0.f;
  #pragma unroll
  for (int t = 0; t < 16; ++t){
    const f32x4* drow = (const f32x4*)&dbc2[0][t][0];
    float s = bdt;
    #pragma unroll
    for (int q = 0; q < 4; ++q){
      f32x4 v = drow[q];
      s += v[0]*wdt[q*4] + v[1]*wdt[q*4+1] + v[2]*wdt[q*4+2] + v[3]*wdt[q*4+3];
    }
    float ldt = (s > 20.f) ? s : __logf(1.f + __expf(s));
    float dtu = ldt * ureg[t];
    ds += ldt;
    f32x4 B0 = drow[4], B1 = drow[5], B2 = drow[6], B3 = drow[7];
    float Bv[16] = {B0[0],B0[1],B0[2],B0[3], B1[0],B1[1],B1[2],B1[3],
                    B2[0],B2[1],B2[2],B2[3], B3[0],B3[1],B3[2],B3[3]};
    #pragma unroll
    for (int k = 0; k < 16; ++k)
      h[k] = __expf(ldt * Aa[k]) * h[k] + dtu * Bv[k];
  }
  #pragma unroll
  for (int s = 0; s < 16; ++s){
    size_t rec = (size_t)c * 8192 + s * 512 + d;
    dAc[rec]  = __expf(ds * Aa[s]);
    hend[rec] = h[s];
  }
}

// ---------------- phase 2: Kogge-Stone over 256 chunk-carries, in-place --------
// lane handles chunks 4l..4l+3; carries written back into hc (= hend buffer).
__global__ __launch_bounds__(256) void scan_p2_k(const float* __restrict__ dAc,
    float* __restrict__ hc){
  const int chain = blockIdx.x * 4 + (threadIdx.x >> 6);   // 0..8191
  const int lane = threadIdx.x & 63;
  const size_t b0 = (size_t)(lane * 4) * 8192 + chain;
  float a0 = dAc[b0], a1 = dAc[b0+8192], a2 = dAc[b0+16384], a3 = dAc[b0+24576];
  float e0 = hc[b0],  e1 = hc[b0+8192],  e2 = hc[b0+16384],  e3 = hc[b0+24576];
  float A = ((a0*a1)*a2)*a3;
  float B = fmaf(a3, fmaf(a2, fmaf(a1, e0, e1), e2), e3);
  #pragma unroll
  for (int dd = 1; dd < 64; dd <<= 1){
    float Ap = __shfl_up(A, dd);
    float Bp = __shfl_up(B, dd);
    if (lane >= dd){ B = fmaf(A, Bp, B); A *= Ap; }
  }
  float Bx = __shfl_up(B, 1);
  if (lane == 0) Bx = 0.f;
  float c0 = Bx;
  float c1 = fmaf(a0, c0, e0);
  float c2 = fmaf(a1, c1, e1);
  float c3 = fmaf(a2, c2, e2);
  hc[b0] = c0; hc[b0+8192] = c1; hc[b0+16384] = c2; hc[b0+24576] = c3;
}

// ---------------- phase 3 + output GEMM: rescan w/ carry, gate, y @ w_out ------
__global__ __launch_bounds__(512, 2) void p3out_k(const float* __restrict__ u,
    const float* __restrict__ z, const float* __restrict__ dbc_g,
    const float* __restrict__ w_dt, const float* __restrict__ b_dt,
    const float* __restrict__ A_log, const float* __restrict__ Dsk,
    const float* __restrict__ carry, const u16* __restrict__ w_outT,
    float* __restrict__ out)
{
  __shared__ u16 yL[16 * 520];            // 16,640 B
  __shared__ float dbcL[16][48];          // 3,072 B (cols 0..15 dt-in, 16..31 B, 32..47 C)
  const int tid = threadIdx.x, d = tid;
  const int c = blockIdx.x, t0 = c * 16;
  for (int i = tid; i < 16*48; i += 512){
    int r = i / 48, j = i % 48;
    dbcL[r][j] = dbc_g[(size_t)(t0 + r)*48 + j];
  }
  float wdt[16];
  #pragma unroll
  for (int r = 0; r < 16; ++r) wdt[r] = w_dt[r*512 + d];
  const float bdt = b_dt[d];
  float Aa[16], h[16];
  #pragma unroll
  for (int s = 0; s < 16; ++s){
    Aa[s] = -__expf(A_log[d*16 + s]);
    h[s]  = carry[(size_t)c * 8192 + s * 512 + d];
  }
  const float dsk = Dsk[d];
  __syncthreads();
  #pragma unroll
  for (int t = 0; t < 16; ++t){
    size_t g = (size_t)(t0 + t)*512 + d;
    float lu = u[g], lz = z[g];
    const f32x4* drow = (const f32x4*)&dbcL[t][0];
    float s = bdt;
    #pragma unroll
    for (int q = 0; q < 4; ++q){
      f32x4 v = drow[q];
      s += v[0]*wdt[q*4] + v[1]*wdt[q*4+1] + v[2]*wdt[q*4+2] + v[3]*wdt[q*4+3];
    }
    float ldt = (s > 20.f) ? s : __logf(1.f + __expf(s));
    float dtu = ldt * lu, y = 0.f;
    f32x4 B0 = drow[4], B1 = drow[5], B2 = drow[6], B3 = drow[7];
    f32x4 C0 = drow[8], C1 = drow[9], C2 = drow[10], C3 = drow[11];
    float Bv[16] = {B0[0],B0[1],B0[2],B0[3], B1[0],B1[1],B1[2],B1[3],
                    B2[0],B2[1],B2[2],B2[3], B3[0],B3[1],B3[2],B3[3]};
    float Cv[16] = {C0[0],C0[1],C0[2],C0[3], C1[0],C1[1],C1[2],C1[3],
                    C2[0],C2[1],C2[2],C2[3], C3[0],C3[1],C3[2],C3[3]};
    #pragma unroll
    for (int k = 0; k < 16; ++k){
      h[k] = __expf(ldt * Aa[k]) * h[k] + dtu * Bv[k];
      y = fmaf(h[k], Cv[k], y);
    }
    yL[t*520 + d] = f2bf((y + lu*dsk) * silu_f(lz));
  }
  __syncthreads();
  // out[16 x 256] = yL[16x512] @ w_out[512x256]; 8 waves x 32 cols each
  const int wave = tid >> 6, lane = tid & 63, lq = lane >> 4, lr = lane & 15;
  f32x4 acc[2] = {f32x4{0.f,0.f,0.f,0.f}, f32x4{0.f,0.f,0.f,0.f}};
  #pragma unroll
  for (int kk = 0; kk < 512; kk += 32){
    bf16x8 aF = *(const bf16x8*)(yL + lr*520 + kk + lq*8);
    #pragma unroll
    for (int ni = 0; ni < 2; ++ni){
      bf16x8 bF = *(const bf16x8*)(w_outT + (size_t)(wave*32 + ni*16 + lr)*512 + kk + lq*8);
      acc[ni] = __builtin_amdgcn_mfma_f32_16x16x32_bf16(aF, bF, acc[ni], 0, 0, 0);
    }
  }
  #pragma unroll
  for (int ni = 0; ni < 2; ++ni)
    #pragma unroll
    for (int r = 0; r < 4; ++r)
      out[(size_t)(t0 + lq*4 + r)*256 + wave*32 + ni*16 + lr] = acc[ni][r];
}

extern "C" void kernel_launch(void* const* d_in, const int* in_sizes, int n_in,
                              void* d_out, int out_size, void* d_ws, size_t ws_size,
                              hipStream_t stream){
  const float* x      = (const float*)d_in[0];
  const float* adj    = (const float*)d_in[1];
  const float* gcn_w  = (const float*)d_in[2];
  const float* gcn_b  = (const float*)d_in[3];
  const float* ln_g   = (const float*)d_in[4];
  const float* ln_b   = (const float*)d_in[5];
  const float* w_in   = (const float*)d_in[6];
  const float* conv_w = (const float*)d_in[7];
  const float* conv_b = (const float*)d_in[8];
  const float* w_xp   = (const float*)d_in[9];
  const float* w_dt   = (const float*)d_in[10];
  const float* b_dt   = (const float*)d_in[11];
  const float* A_log  = (const float*)d_in[12];
  const float* D_skip = (const float*)d_in[13];
  const float* w_out  = (const float*)d_in[14];
  float* out = (float*)d_out;

  // workspace layout (bytes); peak 50,003,968 (same as round-1 proven size).
  char* w = (char*)d_ws;
  u16*   xT     = (u16*)(w + 0);          // 2,097,152
  u16*   gcnT   = (u16*)(w + 2097152);    //   131,072
  u16*   w_inT  = (u16*)(w + 2228224);    //   524,288
  u16*   w_outT = (u16*)(w + 2752512);    //   262,144
  u16*   w_xpT  = (u16*)(w + 3014656);    //    65,536
  float* dbc_g  = (float*)(w + 3080192);  //   786,432
  float* G      = (float*)(w + 3866624);  // 8,388,608 : 2 K-split partials (dead after K3)
  float* zb     = (float*)(w + 3866624);  //   overlay: 8,388,608 (written by K4)
  float* u_g    = (float*)(w + 12255232); // 8,388,608
  float* hn     = (float*)(w + 20643840); // 4,194,304 (dead after K4)
  float* xc     = (float*)(w + 24838144); // 8,388,608 (dead after mid_k)
  float* dAc    = (float*)(w + 33226752); // 8,388,608
  float* hendb  = (float*)(w + 41615360); // 8,388,608 -> end 50,003,968; p2 rewrites as carries

  const long long PART = 4096LL * 256;    // partial-buffer stride (floats)

  // 1: all transposes (incl. w_xp zero-pad)
  prep_k<<<1504, dim3(32, 8), 0, stream>>>(x, gcn_w, w_in, w_out, w_xp,
                                           xT, gcnT, w_inT, w_outT, w_xpT);
  // 2: G[z] = adj @ x partials (M=4096,K=4096,N=256), TM=32, KS=2 -> 256 blocks
  gemm_k<0, 32, 256, 512, 1><<<dim3(128, 1, 2), 512, 23040, stream>>>(
      adj, 4096, 0, xT, 4096, 2048, G, PART, nullptr, nullptr, nullptr, nullptr);
  // 3: hn = LN(relu(sum_z G[z] @ gcn_w + gcn_b))
  gemm_k<1, 16, 256, 256, 2><<<dim3(256, 1, 1), 256, 38336, stream>>>(
      G, 256, PART, gcnT, 256, 256, hn, 0, nullptr, gcn_b, ln_g, ln_b);
  // 4: xz = hn @ w_in -> xc | zb
  gemm_k<2, 32, 128, 256, 1><<<dim3(128, 8, 1), 256, 12800, stream>>>(
      hn, 256, 0, w_inT, 256, 256, xc, 0, zb, nullptr, nullptr, nullptr);
  // 5: fused conv+silu + dbc(MFMA) + dt + scan phase 1 (256 chunks of 16)
  mid_k<<<256, 512, 0, stream>>>(xc, conv_w, conv_b, w_xpT, w_dt, b_dt, A_log,
                                 u_g, dbc_g, dAc, hendb);
  // 6: carry propagation (in-place into hendb)
  scan_p2_k<<<2048, 256, 0, stream>>>(dAc, hendb);
  // 7: fused rescan + gate + y @ w_out -> out
  p3out_k<<<256, 512, 0, stream>>>(u_g, zb, dbc_g, w_dt, b_dt, A_log, D_skip,
                                   hendb, w_outT, out);
}

// Round 5
// 270.924 us; speedup vs baseline: 1.1352x; 1.1352x over previous
//
#include <hip/hip_runtime.h>
#include <cstddef>
#include <cstdint>

typedef unsigned short u16;
typedef __attribute__((ext_vector_type(8))) unsigned short ushort8;
typedef __attribute__((ext_vector_type(8))) short bf16x8;   // 8 bf16 bit-patterns (4 VGPRs)
typedef __attribute__((ext_vector_type(4))) float f32x4;

#define DEV __device__ __forceinline__

DEV u16 f2bf(float f){
  uint32_t u = __builtin_bit_cast(uint32_t, f);
  u += 0x7FFFu + ((u >> 16) & 1u);          // RNE
  return (u16)(u >> 16);
}
DEV float silu_f(float x){ return x / (1.f + __expf(-x)); }

// ---------------- fused transposes: fp32 [R][C] -> bf16 [Cout][R] ----------------
__global__ __launch_bounds__(256) void prep_k(const float* __restrict__ x,
    const float* __restrict__ gcn_w, const float* __restrict__ w_in,
    const float* __restrict__ w_out, const float* __restrict__ w_xp,
    u16* __restrict__ xT, u16* __restrict__ gcnT, u16* __restrict__ w_inT,
    u16* __restrict__ w_outT, u16* __restrict__ w_xpT){
  __shared__ u16 tile[32][33];
  int b = blockIdx.x;
  const float* in; u16* out; int R, C, Cout, bx, by;
  if (b < 1024)      { in=x;     out=xT;     R=4096; C=256;  Cout=256;  bx=b&7;  by=b>>3; }
  else if (b < 1088) { b-=1024; in=gcn_w; out=gcnT;   R=256; C=256;  Cout=256;  bx=b&7;  by=b>>3; }
  else if (b < 1344) { b-=1088; in=w_in;  out=w_inT;  R=256; C=1024; Cout=1024; bx=b&31; by=b>>5; }
  else if (b < 1472) { b-=1344; in=w_out; out=w_outT; R=512; C=256;  Cout=256;  bx=b&7;  by=b>>3; }
  else               { b-=1472; in=w_xp;  out=w_xpT;  R=512; C=48;   Cout=64;   bx=b&1;  by=b>>1; }
  int c0 = bx*32, r0 = by*32, tx = threadIdx.x, ty = threadIdx.y;   // block (32,8)
  #pragma unroll
  for (int k = 0; k < 4; ++k){
    int r = r0 + ty + k*8, c = c0 + tx;
    float v = (c < C) ? in[(size_t)r * C + c] : 0.f;
    tile[ty + k*8][tx] = f2bf(v);
  }
  __syncthreads();
  #pragma unroll
  for (int k = 0; k < 4; ++k){
    int oc = c0 + ty + k*8, orr = r0 + tx;
    if (oc < Cout) out[(size_t)oc * R + orr] = tile[tx][ty + k*8];
  }
}

// ---------------- generic bf16-MFMA GEMM with register-prefetch pipeline ------
// C[M,N] = A_fp32[M,K] @ B, B pre-transposed bf16 [N][K] (ldb=K).
// NPART>1: A is the sum of NPART partial buffers spaced pastr floats apart.
// WPE: __launch_bounds__ min-waves-per-EU (2 -> up to 256 VGPRs).
// MODE: 0 = plain store to out0 + blockIdx.z*postr (256-wide output)
//       1 = +bias, ReLU, LayerNorm(256) -> out0 fp32
//       2 = split store: cols<512 -> out0, else -> out1 (both 512-wide)
template<int MODE, int TM, int NT, int NTHR, int NPART, int WPE>
__global__ __launch_bounds__(NTHR, WPE) void gemm_k(const float* __restrict__ A, int lda, long long pastr,
    const u16* __restrict__ Bt, int ldb, int kchunk,
    float* __restrict__ out0, long long postr, float* __restrict__ out1,
    const float* __restrict__ bias, const float* __restrict__ lng, const float* __restrict__ lnb)
{
  constexpr int NW = NTHR/64, WR = NW/4, WM = TM/WR, WN = NT/4;
  constexpr int MI = WM/16, NI = WN/16;
  extern __shared__ char smem[];
  u16* As = (u16*)smem;                 // TM x 40
  u16* Bs = As + TM * 40;               // NT x 40
  const int tid = threadIdx.x, wave = tid >> 6, lane = tid & 63;
  const int lq = lane >> 4, lr = lane & 15;
  const int wm = wave >> 2, wn = wave & 3;
  const int m0 = blockIdx.x * TM, n0g = blockIdx.y * NT;
  const int k0base = blockIdx.z * kchunk;

  f32x4 acc[MI][NI];
  #pragma unroll
  for (int i = 0; i < MI; ++i)
    #pragma unroll
    for (int j = 0; j < NI; ++j) acc[i][j] = f32x4{0.f, 0.f, 0.f, 0.f};

  const int arow = tid >> 2, ako = (tid & 3) * 8;
  const bool aact = (tid < TM * 4);
  const bool bact = (tid < NT);
  const float* aptr = A + (size_t)(m0 + arow) * lda + k0base + ako;
  const u16*   bptr = Bt + (size_t)(n0g + tid) * ldb + k0base;

  f32x4 fa0[NPART], fa1[NPART];
  ushort8 bv[4];
  if (aact){
    #pragma unroll
    for (int p = 0; p < NPART; ++p){
      fa0[p] = *(const f32x4*)(aptr + (size_t)p * pastr);
      fa1[p] = *(const f32x4*)(aptr + (size_t)p * pastr + 4);
    }
  }
  if (bact){
    const ushort8* bp = (const ushort8*)bptr;
    #pragma unroll
    for (int j = 0; j < 4; ++j) bv[j] = bp[j];
  }

  for (int kk = 0; kk < kchunk; kk += 32){
    if (aact){
      f32x4 s0 = fa0[0], s1 = fa1[0];
      #pragma unroll
      for (int p = 1; p < NPART; ++p){ s0 += fa0[p]; s1 += fa1[p]; }
      ushort8 o;
      #pragma unroll
      for (int j = 0; j < 4; ++j) o[j] = f2bf(s0[j]);
      #pragma unroll
      for (int j = 0; j < 4; ++j) o[4 + j] = f2bf(s1[j]);
      *(ushort8*)(As + arow * 40 + ako) = o;
    }
    if (bact){
      ushort8* dst = (ushort8*)(Bs + tid * 40);
      #pragma unroll
      for (int j = 0; j < 4; ++j) dst[j] = bv[j];
    }
    __syncthreads();
    if (kk + 32 < kchunk){
      aptr += 32; bptr += 32;
      if (aact){
        #pragma unroll
        for (int p = 0; p < NPART; ++p){
          fa0[p] = *(const f32x4*)(aptr + (size_t)p * pastr);
          fa1[p] = *(const f32x4*)(aptr + (size_t)p * pastr + 4);
        }
      }
      if (bact){
        const ushort8* bp = (const ushort8*)bptr;
        #pragma unroll
        for (int j = 0; j < 4; ++j) bv[j] = bp[j];
      }
    }
    bf16x8 af[MI], bfr[NI];
    #pragma unroll
    for (int mi = 0; mi < MI; ++mi)
      af[mi] = *(const bf16x8*)(As + (wm * WM + mi * 16 + lr) * 40 + lq * 8);
    #pragma unroll
    for (int ni = 0; ni < NI; ++ni)
      bfr[ni] = *(const bf16x8*)(Bs + (wn * WN + ni * 16 + lr) * 40 + lq * 8);
    #pragma unroll
    for (int mi = 0; mi < MI; ++mi)
      #pragma unroll
      for (int ni = 0; ni < NI; ++ni)
        acc[mi][ni] = __builtin_amdgcn_mfma_f32_16x16x32_bf16(af[mi], bfr[ni], acc[mi][ni], 0, 0, 0);
    __syncthreads();
  }

  if constexpr (MODE == 1){
    float* Hs  = (float*)(smem + TM * 80 + NT * 80);   // TM x 257
    float* mus = Hs + TM * 257;
    float* rss = mus + TM;
    #pragma unroll
    for (int mi = 0; mi < MI; ++mi)
      #pragma unroll
      for (int ni = 0; ni < NI; ++ni)
        #pragma unroll
        for (int r = 0; r < 4; ++r){
          int row_l = wm*WM + mi*16 + lq*4 + r;
          int col_l = wn*WN + ni*16 + lr;
          Hs[row_l*257 + col_l] = fmaxf(acc[mi][ni][r] + bias[col_l], 0.f);
        }
    __syncthreads();
    for (int r = wave; r < TM; r += NW){
      float s = 0.f, s2 = 0.f;
      #pragma unroll
      for (int j = 0; j < 4; ++j){
        float v = Hs[r*257 + lane + j*64];
        s += v; s2 += v*v;
      }
      #pragma unroll
      for (int d = 32; d; d >>= 1){
        s  += __shfl_down(s, d);
        s2 += __shfl_down(s2, d);
      }
      if (lane == 0){
        float mu  = s * (1.f/256.f);
        float var = s2 * (1.f/256.f) - mu*mu;
        mus[r] = mu; rss[r] = rsqrtf(var + 1e-5f);
      }
    }
    __syncthreads();
    for (int idx = tid; idx < TM*256; idx += NTHR){
      int r = idx >> 8, c = idx & 255;
      float v = (Hs[r*257 + c] - mus[r]) * rss[r] * lng[c] + lnb[c];
      out0[(size_t)(m0 + r) * 256 + c] = v;
    }
  } else {
    #pragma unroll
    for (int mi = 0; mi < MI; ++mi)
      #pragma unroll
      for (int ni = 0; ni < NI; ++ni)
        #pragma unroll
        for (int r = 0; r < 4; ++r){
          float v = acc[mi][ni][r];
          int row  = m0 + wm*WM + mi*16 + lq*4 + r;
          int gcol = n0g + wn*WN + ni*16 + lr;
          if constexpr (MODE == 0){
            out0[(size_t)blockIdx.z * postr + (size_t)row * 256 + gcol] = v;
          } else {
            if (gcol < 512) out0[(size_t)row * 512 + gcol] = v;
            else            out1[(size_t)row * 512 + gcol - 512] = v;
          }
        }
  }
}

// ---------------- fused: conv+silu -> dbc (MFMA) -> dt -> scan phase 1 ----------
// chunk = 16 timesteps; grid 256 blocks x 512 threads; thread = channel d.
// B-matrix values read as LDS broadcasts (same-address, conflict-free) to keep
// per-thread register arrays at ureg/wdt/Aa/h = 64 floats (no spills).
__global__ __launch_bounds__(512, 2) void mid_k(const float* __restrict__ xc,
    const float* __restrict__ cw, const float* __restrict__ cb,
    const u16* __restrict__ w_xpT, const float* __restrict__ w_dt,
    const float* __restrict__ b_dt, const float* __restrict__ A_log,
    float* __restrict__ u_g, float* __restrict__ dbc_g,
    float* __restrict__ dAc, float* __restrict__ hend)
{
  __shared__ u16 uL[16 * 520];            // 16,640 B
  __shared__ float dbc2[2][16][64];       // 8,192 B (reduced in-place into [0])
  const int tid = threadIdx.x, d = tid;
  const int c = blockIdx.x, t0 = c * 16;
  const float w0 = cw[d*4+0], w1 = cw[d*4+1], w2 = cw[d*4+2], w3 = cw[d*4+3];
  const float cbd = cb[d];
  float xm3 = 0.f, xm2 = 0.f, xm1 = 0.f;
  if (c > 0){
    xm3 = xc[(size_t)(t0-3)*512 + d];
    xm2 = xc[(size_t)(t0-2)*512 + d];
    xm1 = xc[(size_t)(t0-1)*512 + d];
  }
  float ureg[16];
  #pragma unroll
  for (int t = 0; t < 16; ++t){
    float x0 = xc[(size_t)(t0+t)*512 + d];
    float a = cbd + xm3*w0 + xm2*w1 + xm1*w2 + x0*w3;
    float uu = silu_f(a);
    ureg[t] = uu;
    uL[t*520 + d] = f2bf(uu);
    u_g[(size_t)(t0+t)*512 + d] = uu;
    xm3 = xm2; xm2 = xm1; xm1 = x0;
  }
  __syncthreads();
  // dbc[16x48(+pad)] = u[16x512] @ w_xp[512x64]; 8 waves = 4 n-tiles x 2 K-halves
  const int wave = tid >> 6, lane = tid & 63, lq = lane >> 4, lr = lane & 15;
  const int nt = wave & 3, kh = wave >> 2;
  f32x4 dacc{0.f, 0.f, 0.f, 0.f};
  #pragma unroll
  for (int kk = kh*256; kk < kh*256 + 256; kk += 32){
    bf16x8 aF = *(const bf16x8*)(uL + lr*520 + kk + lq*8);
    bf16x8 bF = *(const bf16x8*)(w_xpT + (size_t)(nt*16 + lr)*512 + kk + lq*8);
    dacc = __builtin_amdgcn_mfma_f32_16x16x32_bf16(aF, bF, dacc, 0, 0, 0);
  }
  #pragma unroll
  for (int r = 0; r < 4; ++r) dbc2[kh][lq*4 + r][nt*16 + lr] = dacc[r];
  __syncthreads();
  for (int i = tid; i < 16*64; i += 512){
    int r = i >> 6, j = i & 63;
    float v = dbc2[0][r][j] + dbc2[1][r][j];
    dbc2[0][r][j] = v;
    if (j < 48) dbc_g[(size_t)(t0 + r)*48 + j] = v;
  }
  __syncthreads();
  // dt = softplus(dbc[:, :16] @ w_dt + b_dt); local scan from zero state
  float wdt[16];
  #pragma unroll
  for (int r = 0; r < 16; ++r) wdt[r] = w_dt[r*512 + d];
  const float bdt = b_dt[d];
  float Aa[16], h[16];
  #pragma unroll
  for (int s = 0; s < 16; ++s){ Aa[s] = -__expf(A_log[d*16 + s]); h[s] = 0.f; }
  float ds = 0.f;
  #pragma unroll
  for (int t = 0; t < 16; ++t){
    float s = bdt;
    #pragma unroll
    for (int r = 0; r < 16; ++r) s += dbc2[0][t][r] * wdt[r];
    float ldt = (s > 20.f) ? s : __logf(1.f + __expf(s));
    float dtu = ldt * ureg[t];
    ds += ldt;
    #pragma unroll
    for (int k = 0; k < 16; ++k)
      h[k] = __expf(ldt * Aa[k]) * h[k] + dtu * dbc2[0][t][16 + k];
  }
  #pragma unroll
  for (int s = 0; s < 16; ++s){
    size_t rec = (size_t)c * 8192 + s * 512 + d;
    dAc[rec]  = __expf(ds * Aa[s]);
    hend[rec] = h[s];
  }
}

// ---------------- phase 2: Kogge-Stone over 256 chunk-carries, in-place --------
__global__ __launch_bounds__(256) void scan_p2_k(const float* __restrict__ dAc,
    float* __restrict__ hc){
  const int chain = blockIdx.x * 4 + (threadIdx.x >> 6);   // 0..8191
  const int lane = threadIdx.x & 63;
  const size_t b0 = (size_t)(lane * 4) * 8192 + chain;
  float a0 = dAc[b0], a1 = dAc[b0+8192], a2 = dAc[b0+16384], a3 = dAc[b0+24576];
  float e0 = hc[b0],  e1 = hc[b0+8192],  e2 = hc[b0+16384],  e3 = hc[b0+24576];
  float A = ((a0*a1)*a2)*a3;
  float B = fmaf(a3, fmaf(a2, fmaf(a1, e0, e1), e2), e3);
  #pragma unroll
  for (int dd = 1; dd < 64; dd <<= 1){
    float Ap = __shfl_up(A, dd);
    float Bp = __shfl_up(B, dd);
    if (lane >= dd){ B = fmaf(A, Bp, B); A *= Ap; }
  }
  float Bx = __shfl_up(B, 1);
  if (lane == 0) Bx = 0.f;
  float c0 = Bx;
  float c1 = fmaf(a0, c0, e0);
  float c2 = fmaf(a1, c1, e1);
  float c3 = fmaf(a2, c2, e2);
  hc[b0] = c0; hc[b0+8192] = c1; hc[b0+16384] = c2; hc[b0+24576] = c3;
}

// ---------------- phase 3 + output GEMM: rescan w/ carry, gate, y @ w_out ------
__global__ __launch_bounds__(512, 2) void p3out_k(const float* __restrict__ u,
    const float* __restrict__ z, const float* __restrict__ dbc_g,
    const float* __restrict__ w_dt, const float* __restrict__ b_dt,
    const float* __restrict__ A_log, const float* __restrict__ Dsk,
    const float* __restrict__ carry, const u16* __restrict__ w_outT,
    float* __restrict__ out)
{
  __shared__ u16 yL[16 * 520];            // 16,640 B
  __shared__ float dbcL[16][48];          // 3,072 B (0..15 dt-in, 16..31 B, 32..47 C)
  const int tid = threadIdx.x, d = tid;
  const int c = blockIdx.x, t0 = c * 16;
  for (int i = tid; i < 16*48; i += 512){
    int r = i / 48, j = i % 48;
    dbcL[r][j] = dbc_g[(size_t)(t0 + r)*48 + j];
  }
  float wdt[16];
  #pragma unroll
  for (int r = 0; r < 16; ++r) wdt[r] = w_dt[r*512 + d];
  const float bdt = b_dt[d];
  float Aa[16], h[16];
  #pragma unroll
  for (int s = 0; s < 16; ++s){
    Aa[s] = -__expf(A_log[d*16 + s]);
    h[s]  = carry[(size_t)c * 8192 + s * 512 + d];
  }
  const float dsk = Dsk[d];
  __syncthreads();
  #pragma unroll
  for (int t = 0; t < 16; ++t){
    size_t g = (size_t)(t0 + t)*512 + d;
    float lu = u[g], lz = z[g];
    float s = bdt;
    #pragma unroll
    for (int r = 0; r < 16; ++r) s += dbcL[t][r] * wdt[r];
    float ldt = (s > 20.f) ? s : __logf(1.f + __expf(s));
    float dtu = ldt * lu, y = 0.f;
    #pragma unroll
    for (int k = 0; k < 16; ++k){
      h[k] = __expf(ldt * Aa[k]) * h[k] + dtu * dbcL[t][16 + k];
      y = fmaf(h[k], dbcL[t][32 + k], y);
    }
    yL[t*520 + d] = f2bf((y + lu*dsk) * silu_f(lz));
  }
  __syncthreads();
  // out[16 x 256] = yL[16x512] @ w_out[512x256]; 8 waves x 32 cols each
  const int wave = tid >> 6, lane = tid & 63, lq = lane >> 4, lr = lane & 15;
  f32x4 acc[2] = {f32x4{0.f,0.f,0.f,0.f}, f32x4{0.f,0.f,0.f,0.f}};
  #pragma unroll
  for (int kk = 0; kk < 512; kk += 32){
    bf16x8 aF = *(const bf16x8*)(yL + lr*520 + kk + lq*8);
    #pragma unroll
    for (int ni = 0; ni < 2; ++ni){
      bf16x8 bF = *(const bf16x8*)(w_outT + (size_t)(wave*32 + ni*16 + lr)*512 + kk + lq*8);
      acc[ni] = __builtin_amdgcn_mfma_f32_16x16x32_bf16(aF, bF, acc[ni], 0, 0, 0);
    }
  }
  #pragma unroll
  for (int ni = 0; ni < 2; ++ni)
    #pragma unroll
    for (int r = 0; r < 4; ++r)
      out[(size_t)(t0 + lq*4 + r)*256 + wave*32 + ni*16 + lr] = acc[ni][r];
}

extern "C" void kernel_launch(void* const* d_in, const int* in_sizes, int n_in,
                              void* d_out, int out_size, void* d_ws, size_t ws_size,
                              hipStream_t stream){
  const float* x      = (const float*)d_in[0];
  const float* adj    = (const float*)d_in[1];
  const float* gcn_w  = (const float*)d_in[2];
  const float* gcn_b  = (const float*)d_in[3];
  const float* ln_g   = (const float*)d_in[4];
  const float* ln_b   = (const float*)d_in[5];
  const float* w_in   = (const float*)d_in[6];
  const float* conv_w = (const float*)d_in[7];
  const float* conv_b = (const float*)d_in[8];
  const float* w_xp   = (const float*)d_in[9];
  const float* w_dt   = (const float*)d_in[10];
  const float* b_dt   = (const float*)d_in[11];
  const float* A_log  = (const float*)d_in[12];
  const float* D_skip = (const float*)d_in[13];
  const float* w_out  = (const float*)d_in[14];
  float* out = (float*)d_out;

  // workspace layout (bytes); peak 45,809,664 (< proven 50 MB).
  // G = 8 split-K partials (33.5 MB), dead after K3; zb/u_g/xc/dAc overlay it.
  char* w = (char*)d_ws;
  u16*   xT     = (u16*)(w + 0);          // 2,097,152
  u16*   gcnT   = (u16*)(w + 2097152);    //   131,072
  u16*   w_inT  = (u16*)(w + 2228224);    //   524,288
  u16*   w_outT = (u16*)(w + 2752512);    //   262,144
  u16*   w_xpT  = (u16*)(w + 3014656);    //    65,536
  float* dbc_g  = (float*)(w + 3080192);  //   786,432
  float* G      = (float*)(w + 3866624);  // 33,554,432 (8 x 4 MB partials)
  float* zb     = (float*)(w + 3866624);  //   overlay G[0:2]  (written K4)
  float* u_g    = (float*)(w + 12255232); //   overlay G[2:4]  (written mid_k)
  float* xc     = (float*)(w + 20643840); //   overlay G[4:6]  (written K4, dead after mid_k)
  float* dAc    = (float*)(w + 29032448); //   overlay G[6:8]  (written mid_k)
  float* hn     = (float*)(w + 37421056); // 4,194,304 (dead after K4)
  float* hendb  = (float*)(w + 37421056); //   overlay hn+: 8,388,608 -> end 45,809,664
                                          //   (written mid_k after K4; p2 rewrites as carries)

  const long long PART = 4096LL * 256;    // partial-buffer stride (floats)

  // 1: all transposes (incl. w_xp zero-pad)
  prep_k<<<1504, dim3(32, 8), 0, stream>>>(x, gcn_w, w_in, w_out, w_xp,
                                           xT, gcnT, w_inT, w_outT, w_xpT);
  // 2: G[z] = adj @ x partials (M=4096,K=4096,N=256), TM=64/NT=256, KS=8
  //    -> 512 blocks (2/CU), 16 MFMA/wave/iter, 16 iters
  gemm_k<0, 64, 256, 256, 1, 2><<<dim3(64, 1, 8), 256, 25600, stream>>>(
      adj, 4096, 0, xT, 4096, 512, G, PART, nullptr, nullptr, nullptr, nullptr);
  // 3: hn = LN(relu(sum_z G[z] @ gcn_w + gcn_b))
  gemm_k<1, 16, 256, 256, 8, 2><<<dim3(256, 1, 1), 256, 38336, stream>>>(
      G, 256, PART, gcnT, 256, 256, hn, 0, nullptr, gcn_b, ln_g, ln_b);
  // 4: xz = hn @ w_in -> xc | zb
  gemm_k<2, 32, 128, 256, 1, 2><<<dim3(128, 8, 1), 256, 12800, stream>>>(
      hn, 256, 0, w_inT, 256, 256, xc, 0, zb, nullptr, nullptr, nullptr);
  // 5: fused conv+silu + dbc(MFMA) + dt + scan phase 1 (256 chunks of 16)
  mid_k<<<256, 512, 0, stream>>>(xc, conv_w, conv_b, w_xpT, w_dt, b_dt, A_log,
                                 u_g, dbc_g, dAc, hendb);
  // 6: carry propagation (in-place into hendb)
  scan_p2_k<<<2048, 256, 0, stream>>>(dAc, hendb);
  // 7: fused rescan + gate + y @ w_out -> out
  p3out_k<<<256, 512, 0, stream>>>(u_g, zb, dbc_g, w_dt, b_dt, A_log, D_skip,
                                   hendb, w_outT, out);
}